// Round 1
// baseline (546.108 us; speedup 1.0000x reference)
//
#include <hip/hip_runtime.h>
#include <hip/hip_bf16.h>
#include <cstdint>
#include <cstddef>

// ---------------- common types/helpers ----------------
typedef __attribute__((ext_vector_type(8))) short bf16x8;
typedef __attribute__((ext_vector_type(4))) float f32x4;
typedef __attribute__((ext_vector_type(4))) unsigned int u32x4;

__device__ __forceinline__ unsigned short f2bf(float f) {
  __hip_bfloat16 h = __float2bfloat16(f);
  return *reinterpret_cast<unsigned short*>(&h);
}
__device__ __forceinline__ float bf2f(unsigned short u) {
  __hip_bfloat16 h = *reinterpret_cast<__hip_bfloat16*>(&u);
  return __bfloat162float(h);
}

typedef const __attribute__((address_space(1))) void gas_void;
typedef __attribute__((address_space(3))) void las_void;
__device__ __forceinline__ void gload_lds16(const void* g, void* l) {
  __builtin_amdgcn_global_load_lds((gas_void*)g, (las_void*)l, 16, 0, 0);
}

// ---------------- problem constants ----------------
#define S_LEN 2048
#define HID 4096
#define NH 32
#define NKV 8
#define HD 128
#define NQKV 6144           // 4096 + 1024 + 1024
static const float ATT_SCALE = 0.08838834764831845f; // 128^-0.5

// ---------------- kernel: fp32 -> bf16 convert (hidden) ----------------
__global__ void cvt_f32_bf16_kernel(const float* __restrict__ src,
                                    short* __restrict__ dst, int n) {
  int i = (blockIdx.x * 256 + threadIdx.x) * 8;
  if (i >= n) return;
  f32x4 a = *(const f32x4*)(src + i);
  f32x4 b = *(const f32x4*)(src + i + 4);
  unsigned short t[8];
#pragma unroll
  for (int k = 0; k < 4; ++k) { t[k] = f2bf(a[k]); t[4 + k] = f2bf(b[k]); }
  *(u32x4*)(dst + i) = *(const u32x4*)t;
}

// ---------------- kernel: fp32 [K][N] -> bf16 [N][K] transpose-convert --------
// grid: (N/32, K/32), block 256 (32x8)
__global__ void transpose_cvt_kernel(const float* __restrict__ src,
                                     short* __restrict__ dst, int K, int N) {
  __shared__ float tile[32][33];
  int tx = threadIdx.x & 31, ty = threadIdx.x >> 5;
  int bx = blockIdx.x, by = blockIdx.y;
#pragma unroll
  for (int i = 0; i < 4; ++i) {
    int kr = ty + i * 8;
    tile[kr][tx] = src[(size_t)(by * 32 + kr) * N + bx * 32 + tx];
  }
  __syncthreads();
#pragma unroll
  for (int i = 0; i < 4; ++i) {
    int nc = ty + i * 8;
    dst[(size_t)(bx * 32 + nc) * K + by * 32 + tx] = (short)f2bf(tile[tx][nc]);
  }
}

// ---------------- kernel: bf16 GEMM  C[M,N] = A[M,K] * Bt[N,K]^T -------------
// m97 structure: 128x128 tile, BK=32, 4 waves, global_load_lds width 16.
// MODE 0: write fp32 C.   MODE 1: scatter QKV (bf16) with V transposed.
template <int MODE>
__global__ void gemm_bt_kernel(const short* __restrict__ A, const short* __restrict__ Bt,
                               int M, int N, int K,
                               float* __restrict__ Cf,
                               short* __restrict__ qb_, short* __restrict__ kb_,
                               short* __restrict__ vb_) {
  __shared__ short As[128 * 32];
  __shared__ short Bs[128 * 32];
  const int tid = threadIdx.x;
  const int wid = tid >> 6, lane = tid & 63;
  const int brow = blockIdx.y * 128, bcol = blockIdx.x * 128;
  const int wr = wid >> 1, wc = wid & 1;
  const int r = lane & 15, g = lane >> 4;
  const int crow = lane >> 2;        // row within 16-row chunk
  const int ccol = (lane & 3) * 8;   // element col within 32

  f32x4 acc[4][4] = {};

  for (int kk = 0; kk < K; kk += 32) {
    __syncthreads();
#pragma unroll
    for (int i = 0; i < 2; ++i) {
      int c = wid * 2 + i;
      const short* ga = A + (size_t)(brow + c * 16 + crow) * K + kk + ccol;
      const short* gb = Bt + (size_t)(bcol + c * 16 + crow) * K + kk + ccol;
      gload_lds16(ga, &As[c * 512]);
      gload_lds16(gb, &Bs[c * 512]);
    }
    __syncthreads();
    bf16x8 af[4], bf[4];
#pragma unroll
    for (int m = 0; m < 4; ++m)
      af[m] = *(const bf16x8*)&As[(wr * 64 + m * 16 + r) * 32 + g * 8];
#pragma unroll
    for (int n = 0; n < 4; ++n)
      bf[n] = *(const bf16x8*)&Bs[(wc * 64 + n * 16 + r) * 32 + g * 8];
#pragma unroll
    for (int m = 0; m < 4; ++m)
#pragma unroll
      for (int n = 0; n < 4; ++n)
        acc[m][n] = __builtin_amdgcn_mfma_f32_16x16x32_bf16(af[m], bf[n], acc[m][n], 0, 0, 0);
  }

  if (MODE == 0) {
#pragma unroll
    for (int m = 0; m < 4; ++m)
#pragma unroll
      for (int n = 0; n < 4; ++n)
#pragma unroll
        for (int j = 0; j < 4; ++j) {
          int row = brow + wr * 64 + m * 16 + g * 4 + j;
          int col = bcol + wc * 64 + n * 16 + r;
          Cf[(size_t)row * N + col] = acc[m][n][j];
        }
  } else {
    // column block maps to exactly one head (BN=128 == head dim)
    unsigned short* dst;
    bool isv = false;
    if (bcol < 4096) {
      dst = (unsigned short*)qb_ + (size_t)(bcol >> 7) * S_LEN * HD;
    } else if (bcol < 5120) {
      dst = (unsigned short*)kb_ + (size_t)((bcol - 4096) >> 7) * S_LEN * HD;
    } else {
      dst = (unsigned short*)vb_ + (size_t)((bcol - 5120) >> 7) * HD * S_LEN;
      isv = true;
    }
#pragma unroll
    for (int m = 0; m < 4; ++m)
#pragma unroll
      for (int n = 0; n < 4; ++n)
#pragma unroll
        for (int j = 0; j < 4; ++j) {
          int row = brow + wr * 64 + m * 16 + g * 4 + j;  // s
          int d = wc * 64 + n * 16 + r;                   // head dim
          unsigned short v = f2bf(acc[m][n][j]);
          if (!isv) dst[(size_t)row * HD + d] = v;
          else      dst[(size_t)d * S_LEN + row] = v;     // V^T [d][s]
        }
  }
}

// ---------------- kernel: RoPE in place on q_buf [32][S][128], k_buf [8][S][128]
__global__ void rope_kernel(short* __restrict__ qbuf, short* __restrict__ kbuf,
                            const float* __restrict__ cosT, const float* __restrict__ sinT) {
  int idx = blockIdx.x * 256 + threadIdx.x;
  const int total = (NH + NKV) * S_LEN * 64;
  if (idx >= total) return;
  int d = idx & 63;
  int rowi = idx >> 6;
  unsigned short* base;
  if (rowi < NH * S_LEN) base = (unsigned short*)qbuf + (size_t)rowi * HD;
  else base = (unsigned short*)kbuf + (size_t)(rowi - NH * S_LEN) * HD;
  int s = rowi & (S_LEN - 1);
  float x1 = bf2f(base[d]);
  float x2 = bf2f(base[d + 64]);
  float c1 = cosT[s * HD + d],      s1 = sinT[s * HD + d];
  float c2 = cosT[s * HD + d + 64], s2 = sinT[s * HD + d + 64];
  base[d]      = f2bf(x1 * c1 - x2 * s1);
  base[d + 64] = f2bf(x2 * c2 + x1 * s2);
}

// ---------------- kernel: flash attention (causal, GQA 4:1) ----------------
// grid: (32 qblocks, 32 heads), block 256 = 4 waves; wave owns 16 q-rows.
// KVBLK=64. K staged [64][128] XOR-swizzled; V^T staged [128][64] XOR-swizzled.
__global__ __launch_bounds__(256) void attn_kernel(const short* __restrict__ qb_,
                                                   const short* __restrict__ kb_,
                                                   const short* __restrict__ vb_,
                                                   short* __restrict__ ctx) {
  const int h = blockIdx.y;
  const int qb = (int)gridDim.x - 1 - (int)blockIdx.x;  // heavy blocks first
  const int kvh = h >> 2;
  const int tid = threadIdx.x, wid = tid >> 6, lane = tid & 63;
  const int r = lane & 15, g = lane >> 4;

  __shared__ short Ks[64 * 128];
  __shared__ short Vts[128 * 64];
  __shared__ short Ps[4][16 * 64];

  // Q fragments (row = r, k-slice per s4), kept in registers
  const unsigned short* qptr =
      (const unsigned short*)qb_ + ((size_t)h * S_LEN + qb * 64 + wid * 16) * HD;
  bf16x8 qf[4];
#pragma unroll
  for (int s4 = 0; s4 < 4; ++s4)
    qf[s4] = *(const bf16x8*)(qptr + (size_t)r * HD + s4 * 32 + g * 8);

  f32x4 oacc[8] = {};
  float m_run[4], l_run[4];
#pragma unroll
  for (int j = 0; j < 4; ++j) { m_run[j] = -1e30f; l_run[j] = 0.f; }

  for (int kvt = 0; kvt <= qb; ++kvt) {
    __syncthreads();
    // ---- stage K tile and V^T tile (reg-staged, swizzled) ----
#pragma unroll
    for (int i = 0; i < 4; ++i) {
      int c = i * 256 + tid;
      int krow = c >> 4, kcol = c & 15;   // K: 64 rows x 16 chunks
      const unsigned short* gk =
          (const unsigned short*)kb_ + ((size_t)kvh * S_LEN + kvt * 64 + krow) * HD + kcol * 8;
      u32x4 kv4 = *(const u32x4*)gk;
      int koff = (krow * 256 + kcol * 16) ^ ((krow & 7) << 4);
      *(u32x4*)((char*)Ks + koff) = kv4;

      int vrow = c >> 3, vcol = c & 7;    // Vt: 128 rows x 8 chunks
      const unsigned short* gv =
          (const unsigned short*)vb_ + ((size_t)kvh * HD + vrow) * S_LEN + kvt * 64 + vcol * 8;
      u32x4 vv4 = *(const u32x4*)gv;
      int voff = (vrow * 128 + vcol * 16) ^ ((vrow & 7) << 4);
      *(u32x4*)((char*)Vts + voff) = vv4;
    }
    __syncthreads();

    // ---- S = Q K^T (16 MFMA) ----
    f32x4 sv[4] = {};
#pragma unroll
    for (int n = 0; n < 4; ++n) {
      int krow = n * 16 + r;
      int swz = (krow & 7) << 4;
#pragma unroll
      for (int s4 = 0; s4 < 4; ++s4) {
        bf16x8 kf = *(const bf16x8*)((const char*)Ks + ((krow * 256 + s4 * 64 + g * 16) ^ swz));
        sv[n] = __builtin_amdgcn_mfma_f32_16x16x32_bf16(qf[s4], kf, sv[n], 0, 0, 0);
      }
    }

    // ---- scale + causal mask ----
    if (kvt == qb) {
#pragma unroll
      for (int n = 0; n < 4; ++n)
#pragma unroll
        for (int j = 0; j < 4; ++j) {
          int colg = kvt * 64 + n * 16 + r;
          int rowg = qb * 64 + wid * 16 + g * 4 + j;
          sv[n][j] = (colg <= rowg) ? sv[n][j] * ATT_SCALE : -1e30f;
        }
    } else {
#pragma unroll
      for (int n = 0; n < 4; ++n)
#pragma unroll
        for (int j = 0; j < 4; ++j) sv[n][j] *= ATT_SCALE;
    }

    // ---- online softmax (row = 16-lane group) ----
    float pmax[4];
#pragma unroll
    for (int j = 0; j < 4; ++j)
      pmax[j] = fmaxf(fmaxf(sv[0][j], sv[1][j]), fmaxf(sv[2][j], sv[3][j]));
#pragma unroll
    for (int msk = 1; msk <= 8; msk <<= 1)
#pragma unroll
      for (int j = 0; j < 4; ++j) pmax[j] = fmaxf(pmax[j], __shfl_xor(pmax[j], msk));

    float sf[4], rsum[4];
#pragma unroll
    for (int j = 0; j < 4; ++j) {
      float mn = fmaxf(m_run[j], pmax[j]);
      sf[j] = __expf(m_run[j] - mn);
      m_run[j] = mn;
      rsum[j] = 0.f;
    }
#pragma unroll
    for (int n = 0; n < 4; ++n)
#pragma unroll
      for (int j = 0; j < 4; ++j) {
        float p = __expf(sv[n][j] - m_run[j]);
        sv[n][j] = p;
        rsum[j] += p;
      }
#pragma unroll
    for (int msk = 1; msk <= 8; msk <<= 1)
#pragma unroll
      for (int j = 0; j < 4; ++j) rsum[j] += __shfl_xor(rsum[j], msk);
#pragma unroll
    for (int j = 0; j < 4; ++j) l_run[j] = l_run[j] * sf[j] + rsum[j];
#pragma unroll
    for (int t = 0; t < 8; ++t)
#pragma unroll
      for (int j = 0; j < 4; ++j) oacc[t][j] *= sf[j];

    // ---- P -> LDS (bf16, swizzled), per-wave private region ----
#pragma unroll
    for (int n = 0; n < 4; ++n)
#pragma unroll
      for (int j = 0; j < 4; ++j) {
        int prow = g * 4 + j, pcol = n * 16 + r;
        int poff = (prow * 128 + pcol * 2) ^ ((prow & 7) << 4);
        *(unsigned short*)((char*)&Ps[wid][0] + poff) = f2bf(sv[n][j]);
      }

    // ---- O += P V (16 MFMA) ----
#pragma unroll
    for (int s4 = 0; s4 < 2; ++s4) {
      bf16x8 pf = *(const bf16x8*)((const char*)&Ps[wid][0] +
                                   ((r * 128 + s4 * 64 + g * 16) ^ ((r & 7) << 4)));
#pragma unroll
      for (int t = 0; t < 8; ++t) {
        int vrow = t * 16 + r;
        bf16x8 vf = *(const bf16x8*)((const char*)Vts +
                                     ((vrow * 128 + s4 * 64 + g * 16) ^ ((vrow & 7) << 4)));
        oacc[t] = __builtin_amdgcn_mfma_f32_16x16x32_bf16(pf, vf, oacc[t], 0, 0, 0);
      }
    }
  }

  // ---- epilogue: ctx[s][h*128+d] bf16 ----
  float inv[4];
#pragma unroll
  for (int j = 0; j < 4; ++j) inv[j] = 1.0f / l_run[j];
#pragma unroll
  for (int t = 0; t < 8; ++t)
#pragma unroll
    for (int j = 0; j < 4; ++j) {
      int rowg = qb * 64 + wid * 16 + g * 4 + j;
      int colg = h * HD + t * 16 + r;
      ((unsigned short*)ctx)[(size_t)rowg * HID + colg] = f2bf(oacc[t][j] * inv[j]);
    }
}

// ---------------- launcher ----------------
extern "C" void kernel_launch(void* const* d_in, const int* in_sizes, int n_in,
                              void* d_out, int out_size, void* d_ws, size_t ws_size,
                              hipStream_t stream) {
  const float* hidden = (const float*)d_in[0];
  const float* cosT   = (const float*)d_in[1];
  const float* sinT   = (const float*)d_in[2];
  // d_in[3] = causal mask (implemented analytically)
  const float* Wq = (const float*)d_in[4];
  const float* Wk = (const float*)d_in[5];
  const float* Wv = (const float*)d_in[6];
  const float* Wo = (const float*)d_in[7];
  float* out = (float*)d_out;

  char* ws = (char*)d_ws;
  short* hid_bf = (short*)(ws);                        // 16 MB
  short* Wcat   = (short*)(ws + 16777216);             // 48 MB  [6144][4096] bf16 (B^T)
  short* WoT    = (short*)(ws + 67108864);             // 32 MB  [4096][4096] bf16 (B^T)
  short* qbuf   = (short*)(ws + 100663296);            // 16 MB  [32][2048][128]
  short* kbuf   = (short*)(ws + 117440512);            // 4 MB   [8][2048][128]
  short* vbuf   = (short*)(ws + 121634816);            // 4 MB   [8][128][2048] (V^T)
  short* ctx    = (short*)(ws + 125829120);            // 16 MB  [2048][4096]

  // 1) convert hidden fp32 -> bf16
  cvt_f32_bf16_kernel<<<4096, 256, 0, stream>>>(hidden, hid_bf, S_LEN * HID);

  // 2) transpose-convert weights into B^T bf16 layout
  transpose_cvt_kernel<<<dim3(128, 128), 256, 0, stream>>>(Wq, Wcat, HID, 4096);
  transpose_cvt_kernel<<<dim3(32, 128), 256, 0, stream>>>(Wk, Wcat + (size_t)4096 * HID, HID, 1024);
  transpose_cvt_kernel<<<dim3(32, 128), 256, 0, stream>>>(Wv, Wcat + (size_t)5120 * HID, HID, 1024);
  transpose_cvt_kernel<<<dim3(128, 128), 256, 0, stream>>>(Wo, WoT, HID, 4096);

  // 3) QKV projection GEMM (M=2048, N=6144, K=4096), scatter epilogue
  gemm_bt_kernel<1><<<dim3(48, 16), 256, 0, stream>>>(hid_bf, Wcat, S_LEN, NQKV, HID,
                                                      nullptr, qbuf, kbuf, vbuf);

  // 4) RoPE on Q and K
  rope_kernel<<<20480, 256, 0, stream>>>(qbuf, kbuf, cosT, sinT);

  // 5) causal GQA flash attention -> ctx bf16 [2048][4096]
  attn_kernel<<<dim3(32, 32), 256, 0, stream>>>(qbuf, kbuf, vbuf, ctx);

  // 6) output projection GEMM -> fp32 out
  gemm_bt_kernel<0><<<dim3(32, 16), 256, 0, stream>>>(ctx, WoT, S_LEN, HID, HID,
                                                      out, nullptr, nullptr, nullptr);
}

// Round 2
// 420.048 us; speedup vs baseline: 1.3001x; 1.3001x over previous
//
#include <hip/hip_runtime.h>
#include <hip/hip_bf16.h>
#include <cstdint>
#include <cstddef>

// ---------------- common types/helpers ----------------
typedef __attribute__((ext_vector_type(8))) short bf16x8;
typedef __attribute__((ext_vector_type(4))) float f32x4;
typedef __attribute__((ext_vector_type(4))) unsigned int u32x4;

__device__ __forceinline__ unsigned short f2bf(float f) {
  __hip_bfloat16 h = __float2bfloat16(f);
  return *reinterpret_cast<unsigned short*>(&h);
}
__device__ __forceinline__ float bf2f(unsigned short u) {
  __hip_bfloat16 h = *reinterpret_cast<__hip_bfloat16*>(&u);
  return __bfloat162float(h);
}

typedef const __attribute__((address_space(1))) void gas_void;
typedef __attribute__((address_space(3))) void las_void;
__device__ __forceinline__ void gload_lds16(const void* g, void* l) {
  __builtin_amdgcn_global_load_lds((gas_void*)g, (las_void*)l, 16, 0, 0);
}

// ---------------- problem constants ----------------
#define S_LEN 2048
#define HID 4096
#define NH 32
#define NKV 8
#define HD 128
#define NQKV 6144           // 4096 + 1024 + 1024
static const float ATT_SCALE = 0.08838834764831845f; // 128^-0.5

// ---------------- kernel: fp32 -> bf16 convert (hidden) ----------------
__global__ void cvt_f32_bf16_kernel(const float* __restrict__ src,
                                    short* __restrict__ dst, int n) {
  int i = (blockIdx.x * 256 + threadIdx.x) * 8;
  if (i >= n) return;
  f32x4 a = *(const f32x4*)(src + i);
  f32x4 b = *(const f32x4*)(src + i + 4);
  unsigned short t[8];
#pragma unroll
  for (int k = 0; k < 4; ++k) { t[k] = f2bf(a[k]); t[4 + k] = f2bf(b[k]); }
  *(u32x4*)(dst + i) = *(const u32x4*)t;
}

// ---------------- kernel: fp32 [K][N] -> bf16 [N][K] transpose-convert --------
// grid: (N/32, K/32), block 256 (32x8)
__global__ void transpose_cvt_kernel(const float* __restrict__ src,
                                     short* __restrict__ dst, int K, int N) {
  __shared__ float tile[32][33];
  int tx = threadIdx.x & 31, ty = threadIdx.x >> 5;
  int bx = blockIdx.x, by = blockIdx.y;
#pragma unroll
  for (int i = 0; i < 4; ++i) {
    int kr = ty + i * 8;
    tile[kr][tx] = src[(size_t)(by * 32 + kr) * N + bx * 32 + tx];
  }
  __syncthreads();
#pragma unroll
  for (int i = 0; i < 4; ++i) {
    int nc = ty + i * 8;
    dst[(size_t)(bx * 32 + nc) * K + by * 32 + tx] = (short)f2bf(tile[tx][nc]);
  }
}

// ---------------- kernel: bf16 GEMM  C[M,N] = A[M,K] * Bt[N,K]^T -------------
// m97 structure: 128x128 tile, BK=32, 4 waves, global_load_lds width 16.
// MODE 0: write fp32 C.   MODE 1: scatter QKV (bf16) with V transposed.
template <int MODE>
__global__ void gemm_bt_kernel(const short* __restrict__ A, const short* __restrict__ Bt,
                               int M, int N, int K,
                               float* __restrict__ Cf,
                               short* __restrict__ qb_, short* __restrict__ kb_,
                               short* __restrict__ vb_) {
  __shared__ short As[128 * 32];
  __shared__ short Bs[128 * 32];
  const int tid = threadIdx.x;
  const int wid = tid >> 6, lane = tid & 63;
  const int brow = blockIdx.y * 128, bcol = blockIdx.x * 128;
  const int wr = wid >> 1, wc = wid & 1;
  const int r = lane & 15, g = lane >> 4;
  const int crow = lane >> 2;        // row within 16-row chunk
  const int ccol = (lane & 3) * 8;   // element col within 32

  f32x4 acc[4][4] = {};

  for (int kk = 0; kk < K; kk += 32) {
    __syncthreads();
#pragma unroll
    for (int i = 0; i < 2; ++i) {
      int c = wid * 2 + i;
      const short* ga = A + (size_t)(brow + c * 16 + crow) * K + kk + ccol;
      const short* gb = Bt + (size_t)(bcol + c * 16 + crow) * K + kk + ccol;
      gload_lds16(ga, &As[c * 512]);
      gload_lds16(gb, &Bs[c * 512]);
    }
    __syncthreads();
    bf16x8 af[4], bf[4];
#pragma unroll
    for (int m = 0; m < 4; ++m)
      af[m] = *(const bf16x8*)&As[(wr * 64 + m * 16 + r) * 32 + g * 8];
#pragma unroll
    for (int n = 0; n < 4; ++n)
      bf[n] = *(const bf16x8*)&Bs[(wc * 64 + n * 16 + r) * 32 + g * 8];
#pragma unroll
    for (int m = 0; m < 4; ++m)
#pragma unroll
      for (int n = 0; n < 4; ++n)
        acc[m][n] = __builtin_amdgcn_mfma_f32_16x16x32_bf16(af[m], bf[n], acc[m][n], 0, 0, 0);
  }

  if (MODE == 0) {
#pragma unroll
    for (int m = 0; m < 4; ++m)
#pragma unroll
      for (int n = 0; n < 4; ++n)
#pragma unroll
        for (int j = 0; j < 4; ++j) {
          int row = brow + wr * 64 + m * 16 + g * 4 + j;
          int col = bcol + wc * 64 + n * 16 + r;
          Cf[(size_t)row * N + col] = acc[m][n][j];
        }
  } else {
    // column block maps to exactly one head (BN=128 == head dim)
    unsigned short* dst;
    bool isv = false;
    if (bcol < 4096) {
      dst = (unsigned short*)qb_ + (size_t)(bcol >> 7) * S_LEN * HD;
    } else if (bcol < 5120) {
      dst = (unsigned short*)kb_ + (size_t)((bcol - 4096) >> 7) * S_LEN * HD;
    } else {
      dst = (unsigned short*)vb_ + (size_t)((bcol - 5120) >> 7) * HD * S_LEN;
      isv = true;
    }
#pragma unroll
    for (int m = 0; m < 4; ++m)
#pragma unroll
      for (int n = 0; n < 4; ++n)
#pragma unroll
        for (int j = 0; j < 4; ++j) {
          int row = brow + wr * 64 + m * 16 + g * 4 + j;  // s
          int d = wc * 64 + n * 16 + r;                   // head dim
          unsigned short v = f2bf(acc[m][n][j]);
          if (!isv) dst[(size_t)row * HD + d] = v;
          else      dst[(size_t)d * S_LEN + row] = v;     // V^T [d][s]
        }
  }
}

// ---------------- kernel: RoPE in place on q_buf [32][S][128], k_buf [8][S][128]
__global__ void rope_kernel(short* __restrict__ qbuf, short* __restrict__ kbuf,
                            const float* __restrict__ cosT, const float* __restrict__ sinT) {
  int idx = blockIdx.x * 256 + threadIdx.x;
  const int total = (NH + NKV) * S_LEN * 64;
  if (idx >= total) return;
  int d = idx & 63;
  int rowi = idx >> 6;
  unsigned short* base;
  if (rowi < NH * S_LEN) base = (unsigned short*)qbuf + (size_t)rowi * HD;
  else base = (unsigned short*)kbuf + (size_t)(rowi - NH * S_LEN) * HD;
  int s = rowi & (S_LEN - 1);
  float x1 = bf2f(base[d]);
  float x2 = bf2f(base[d + 64]);
  float c1 = cosT[s * HD + d],      s1 = sinT[s * HD + d];
  float c2 = cosT[s * HD + d + 64], s2 = sinT[s * HD + d + 64];
  base[d]      = f2bf(x1 * c1 - x2 * s1);
  base[d + 64] = f2bf(x2 * c2 + x1 * s2);
}

// ---------------- kernel: flash attention (causal, GQA 4:1) ----------------
// grid: (16 qblock-pairs, 32 heads), block 256 = 4 waves; wave owns 16 q-rows.
// Block processes qb=pair and qb=31-pair (33 tiles total -> uniform load).
// KVBLK=64. K staged [64][128] XOR-swizzled; V^T staged [128][64] XOR-swizzled.
// Reg-prefetch of next K/V tile overlaps HBM/L2 latency with compute (T14).
__global__ __launch_bounds__(256) void attn_kernel(const short* __restrict__ qb_,
                                                   const short* __restrict__ kb_,
                                                   const short* __restrict__ vb_,
                                                   short* __restrict__ ctx) {
  const int h = blockIdx.y;
  const int pairIdx = blockIdx.x;   // 0..15
  const int kvh = h >> 2;
  const int tid = threadIdx.x, wid = tid >> 6, lane = tid & 63;
  const int r = lane & 15, g = lane >> 4;

  __shared__ short Ks[64 * 128];
  __shared__ short Vts[128 * 64];
  __shared__ short Ps[4][16 * 64];

  const unsigned short* kb = (const unsigned short*)kb_;
  const unsigned short* vb = (const unsigned short*)vb_;

  // prefetch registers + per-chunk coords
  u32x4 kpre[4], vpre[4];
  int krow_[4], kcol_[4], vrow_[4], vcol_[4];
#pragma unroll
  for (int i = 0; i < 4; ++i) {
    int c = i * 256 + tid;
    krow_[i] = c >> 4; kcol_[i] = c & 15;   // K: 64 rows x 16 chunks of 16B
    vrow_[i] = c >> 3; vcol_[i] = c & 7;    // Vt: 128 rows x 8 chunks of 16B
  }

  auto load_tile = [&](int kvt) {
#pragma unroll
    for (int i = 0; i < 4; ++i) {
      kpre[i] = *(const u32x4*)(kb + ((size_t)kvh * S_LEN + kvt * 64 + krow_[i]) * HD + kcol_[i] * 8);
      vpre[i] = *(const u32x4*)(vb + ((size_t)kvh * HD + vrow_[i]) * S_LEN + kvt * 64 + vcol_[i] * 8);
    }
  };

  load_tile(0);  // prologue: tile 0 of section 0

  for (int sec = 0; sec < 2; ++sec) {
    const int qb = (sec == 0) ? pairIdx : 31 - pairIdx;
    const int nt = qb + 1;

    // Q fragments (row = r, k-slice per s4), kept in registers
    const unsigned short* qptr =
        (const unsigned short*)qb_ + ((size_t)h * S_LEN + qb * 64 + wid * 16) * HD;
    bf16x8 qf[4];
#pragma unroll
    for (int s4 = 0; s4 < 4; ++s4)
      qf[s4] = *(const bf16x8*)(qptr + (size_t)r * HD + s4 * 32 + g * 8);

    f32x4 oacc[8] = {};
    float m_run[4], l_run[4];
#pragma unroll
    for (int j = 0; j < 4; ++j) { m_run[j] = -1e30f; l_run[j] = 0.f; }

    for (int kvt = 0; kvt < nt; ++kvt) {
      __syncthreads();  // previous tile's compute (or prior section) done with LDS
      // ---- write prefetched regs -> LDS (swizzled) ----
#pragma unroll
      for (int i = 0; i < 4; ++i) {
        int koff = (krow_[i] * 256 + kcol_[i] * 16) ^ ((krow_[i] & 7) << 4);
        *(u32x4*)((char*)Ks + koff) = kpre[i];
        int voff = (vrow_[i] * 128 + vcol_[i] * 16) ^ ((vrow_[i] & 7) << 4);
        *(u32x4*)((char*)Vts + voff) = vpre[i];
      }
      __syncthreads();

      // ---- issue next tile's loads (overlap with compute below) ----
      if (kvt + 1 < nt) load_tile(kvt + 1);
      else if (sec == 0) load_tile(0);  // section 1, tile 0

      // ---- S = Q K^T (16 MFMA) ----
      f32x4 sv[4] = {};
      __builtin_amdgcn_s_setprio(1);
#pragma unroll
      for (int n = 0; n < 4; ++n) {
        int krow = n * 16 + r;
        int swz = (krow & 7) << 4;
#pragma unroll
        for (int s4 = 0; s4 < 4; ++s4) {
          bf16x8 kf = *(const bf16x8*)((const char*)Ks + ((krow * 256 + s4 * 64 + g * 16) ^ swz));
          sv[n] = __builtin_amdgcn_mfma_f32_16x16x32_bf16(qf[s4], kf, sv[n], 0, 0, 0);
        }
      }
      __builtin_amdgcn_s_setprio(0);

      // ---- scale + causal mask ----
      if (kvt == qb) {
#pragma unroll
        for (int n = 0; n < 4; ++n)
#pragma unroll
          for (int j = 0; j < 4; ++j) {
            int colg = kvt * 64 + n * 16 + r;
            int rowg = qb * 64 + wid * 16 + g * 4 + j;
            sv[n][j] = (colg <= rowg) ? sv[n][j] * ATT_SCALE : -1e30f;
          }
      } else {
#pragma unroll
        for (int n = 0; n < 4; ++n)
#pragma unroll
          for (int j = 0; j < 4; ++j) sv[n][j] *= ATT_SCALE;
      }

      // ---- online softmax (row = 16-lane group) ----
      float pmax[4];
#pragma unroll
      for (int j = 0; j < 4; ++j)
        pmax[j] = fmaxf(fmaxf(sv[0][j], sv[1][j]), fmaxf(sv[2][j], sv[3][j]));
#pragma unroll
      for (int msk = 1; msk <= 8; msk <<= 1)
#pragma unroll
        for (int j = 0; j < 4; ++j) pmax[j] = fmaxf(pmax[j], __shfl_xor(pmax[j], msk));

      float sf[4], rsum[4];
#pragma unroll
      for (int j = 0; j < 4; ++j) {
        float mn = fmaxf(m_run[j], pmax[j]);
        sf[j] = __expf(m_run[j] - mn);
        m_run[j] = mn;
        rsum[j] = 0.f;
      }
#pragma unroll
      for (int n = 0; n < 4; ++n)
#pragma unroll
        for (int j = 0; j < 4; ++j) {
          float p = __expf(sv[n][j] - m_run[j]);
          sv[n][j] = p;
          rsum[j] += p;
        }
#pragma unroll
      for (int msk = 1; msk <= 8; msk <<= 1)
#pragma unroll
        for (int j = 0; j < 4; ++j) rsum[j] += __shfl_xor(rsum[j], msk);
#pragma unroll
      for (int j = 0; j < 4; ++j) l_run[j] = l_run[j] * sf[j] + rsum[j];
#pragma unroll
      for (int t = 0; t < 8; ++t)
#pragma unroll
        for (int j = 0; j < 4; ++j) oacc[t][j] *= sf[j];

      // ---- P -> LDS (bf16, swizzled), per-wave private region ----
#pragma unroll
      for (int n = 0; n < 4; ++n)
#pragma unroll
        for (int j = 0; j < 4; ++j) {
          int prow = g * 4 + j, pcol = n * 16 + r;
          int poff = (prow * 128 + pcol * 2) ^ ((prow & 7) << 4);
          *(unsigned short*)((char*)&Ps[wid][0] + poff) = f2bf(sv[n][j]);
        }

      // ---- O += P V (16 MFMA) ----
      __builtin_amdgcn_s_setprio(1);
#pragma unroll
      for (int s4 = 0; s4 < 2; ++s4) {
        bf16x8 pf = *(const bf16x8*)((const char*)&Ps[wid][0] +
                                     ((r * 128 + s4 * 64 + g * 16) ^ ((r & 7) << 4)));
#pragma unroll
        for (int t = 0; t < 8; ++t) {
          int vrow = t * 16 + r;
          bf16x8 vf = *(const bf16x8*)((const char*)Vts +
                                       ((vrow * 128 + s4 * 64 + g * 16) ^ ((vrow & 7) << 4)));
          oacc[t] = __builtin_amdgcn_mfma_f32_16x16x32_bf16(pf, vf, oacc[t], 0, 0, 0);
        }
      }
      __builtin_amdgcn_s_setprio(0);
    }

    // ---- epilogue: ctx[s][h*128+d] bf16 ----
    float inv[4];
#pragma unroll
    for (int j = 0; j < 4; ++j) inv[j] = 1.0f / l_run[j];
#pragma unroll
    for (int t = 0; t < 8; ++t)
#pragma unroll
      for (int j = 0; j < 4; ++j) {
        int rowg = qb * 64 + wid * 16 + g * 4 + j;
        int colg = h * HD + t * 16 + r;
        ((unsigned short*)ctx)[(size_t)rowg * HID + colg] = f2bf(oacc[t][j] * inv[j]);
      }
  }
}

// ---------------- launcher ----------------
extern "C" void kernel_launch(void* const* d_in, const int* in_sizes, int n_in,
                              void* d_out, int out_size, void* d_ws, size_t ws_size,
                              hipStream_t stream) {
  const float* hidden = (const float*)d_in[0];
  const float* cosT   = (const float*)d_in[1];
  const float* sinT   = (const float*)d_in[2];
  // d_in[3] = causal mask (implemented analytically)
  const float* Wq = (const float*)d_in[4];
  const float* Wk = (const float*)d_in[5];
  const float* Wv = (const float*)d_in[6];
  const float* Wo = (const float*)d_in[7];
  float* out = (float*)d_out;

  char* ws = (char*)d_ws;
  short* hid_bf = (short*)(ws);                        // 16 MB
  short* Wcat   = (short*)(ws + 16777216);             // 48 MB  [6144][4096] bf16 (B^T)
  short* WoT    = (short*)(ws + 67108864);             // 32 MB  [4096][4096] bf16 (B^T)
  short* qbuf   = (short*)(ws + 100663296);            // 16 MB  [32][2048][128]
  short* kbuf   = (short*)(ws + 117440512);            // 4 MB   [8][2048][128]
  short* vbuf   = (short*)(ws + 121634816);            // 4 MB   [8][128][2048] (V^T)
  short* ctx    = (short*)(ws + 125829120);            // 16 MB  [2048][4096]

  // 1) convert hidden fp32 -> bf16
  cvt_f32_bf16_kernel<<<4096, 256, 0, stream>>>(hidden, hid_bf, S_LEN * HID);

  // 2) transpose-convert weights into B^T bf16 layout
  transpose_cvt_kernel<<<dim3(128, 128), 256, 0, stream>>>(Wq, Wcat, HID, 4096);
  transpose_cvt_kernel<<<dim3(32, 128), 256, 0, stream>>>(Wk, Wcat + (size_t)4096 * HID, HID, 1024);
  transpose_cvt_kernel<<<dim3(32, 128), 256, 0, stream>>>(Wv, Wcat + (size_t)5120 * HID, HID, 1024);
  transpose_cvt_kernel<<<dim3(128, 128), 256, 0, stream>>>(Wo, WoT, HID, 4096);

  // 3) QKV projection GEMM (M=2048, N=6144, K=4096), scatter epilogue
  gemm_bt_kernel<1><<<dim3(48, 16), 256, 0, stream>>>(hid_bf, Wcat, S_LEN, NQKV, HID,
                                                      nullptr, qbuf, kbuf, vbuf);

  // 4) RoPE on Q and K
  rope_kernel<<<20480, 256, 0, stream>>>(qbuf, kbuf, cosT, sinT);

  // 5) causal GQA flash attention -> ctx bf16 [2048][4096]
  attn_kernel<<<dim3(16, 32), 256, 0, stream>>>(qbuf, kbuf, vbuf, ctx);

  // 6) output projection GEMM -> fp32 out
  gemm_bt_kernel<0><<<dim3(32, 16), 256, 0, stream>>>(ctx, WoT, S_LEN, HID, HID,
                                                      out, nullptr, nullptr, nullptr);
}

// Round 3
// 413.540 us; speedup vs baseline: 1.3206x; 1.0157x over previous
//
#include <hip/hip_runtime.h>
#include <hip/hip_bf16.h>
#include <cstdint>
#include <cstddef>

// ---------------- common types/helpers ----------------
typedef __attribute__((ext_vector_type(8))) short bf16x8;
typedef __attribute__((ext_vector_type(4))) float f32x4;
typedef __attribute__((ext_vector_type(4))) unsigned int u32x4;

__device__ __forceinline__ unsigned short f2bf(float f) {
  __hip_bfloat16 h = __float2bfloat16(f);
  return *reinterpret_cast<unsigned short*>(&h);
}
__device__ __forceinline__ float bf2f(unsigned short u) {
  __hip_bfloat16 h = *reinterpret_cast<__hip_bfloat16*>(&u);
  return __bfloat162float(h);
}

typedef const __attribute__((address_space(1))) void gas_void;
typedef __attribute__((address_space(3))) void las_void;
__device__ __forceinline__ void gload_lds16(const void* g, void* l) {
  __builtin_amdgcn_global_load_lds((gas_void*)g, (las_void*)l, 16, 0, 0);
}

// ---------------- problem constants ----------------
#define S_LEN 2048
#define HID 4096
#define NH 32
#define NKV 8
#define HD 128
#define NQKV 6144           // 4096 + 1024 + 1024
static const float ATT_SCALE = 0.08838834764831845f; // 128^-0.5

// K global layout: [kvh][kvt(32)][16KB tile], element (krow=s&63, d) at byte
//   (((krow<<8) + ((d>>3)<<4)) ^ ((krow&7)<<4)) + ((d&7)<<1)
// V global layout: [kvh][kvt(32)][16KB tile], element (vrow=d, sl=s&63) at byte
//   (((vrow<<7) + ((sl>>3)<<4)) ^ ((vrow&7)<<4)) + ((sl&7)<<1)
// These equal the swizzled LDS image, so global_load_lds (linear dest) +
// swizzled ds_read in attn is correct (both-sides swizzle, rule 21).

// ---------------- kernel: fp32 -> bf16 convert (hidden) ----------------
__global__ void cvt_f32_bf16_kernel(const float* __restrict__ src,
                                    short* __restrict__ dst, int n) {
  int i = (blockIdx.x * 256 + threadIdx.x) * 8;
  if (i >= n) return;
  f32x4 a = *(const f32x4*)(src + i);
  f32x4 b = *(const f32x4*)(src + i + 4);
  unsigned short t[8];
#pragma unroll
  for (int k = 0; k < 4; ++k) { t[k] = f2bf(a[k]); t[4 + k] = f2bf(b[k]); }
  *(u32x4*)(dst + i) = *(const u32x4*)t;
}

// ---------------- kernel: fp32 [K][N] -> bf16 [N][K] transpose-convert --------
// grid: (N/32, K/32), block 256 (32x8)
__global__ void transpose_cvt_kernel(const float* __restrict__ src,
                                     short* __restrict__ dst, int K, int N) {
  __shared__ float tile[32][33];
  int tx = threadIdx.x & 31, ty = threadIdx.x >> 5;
  int bx = blockIdx.x, by = blockIdx.y;
#pragma unroll
  for (int i = 0; i < 4; ++i) {
    int kr = ty + i * 8;
    tile[kr][tx] = src[(size_t)(by * 32 + kr) * N + bx * 32 + tx];
  }
  __syncthreads();
#pragma unroll
  for (int i = 0; i < 4; ++i) {
    int nc = ty + i * 8;
    dst[(size_t)(bx * 32 + nc) * K + by * 32 + tx] = (short)f2bf(tile[tx][nc]);
  }
}

// ---------------- kernel: bf16 GEMM  C[M,N] = A[M,K] * Bt[N,K]^T -------------
// m97 structure: 128x128 tile, BK=32, 4 waves, global_load_lds width 16.
// MODE 0: write fp32 C.   MODE 1: scatter QKV (bf16): Q row-major,
//                                 K/V in pre-swizzled tiled layout (see top).
template <int MODE>
__global__ void gemm_bt_kernel(const short* __restrict__ A, const short* __restrict__ Bt,
                               int M, int N, int K,
                               float* __restrict__ Cf,
                               short* __restrict__ qb_, short* __restrict__ kb_,
                               short* __restrict__ vb_) {
  __shared__ short As[128 * 32];
  __shared__ short Bs[128 * 32];
  const int tid = threadIdx.x;
  const int wid = tid >> 6, lane = tid & 63;
  const int brow = blockIdx.y * 128, bcol = blockIdx.x * 128;
  const int wr = wid >> 1, wc = wid & 1;
  const int r = lane & 15, g = lane >> 4;
  const int crow = lane >> 2;        // row within 16-row chunk
  const int ccol = (lane & 3) * 8;   // element col within 32

  f32x4 acc[4][4] = {};

  for (int kk = 0; kk < K; kk += 32) {
    __syncthreads();
#pragma unroll
    for (int i = 0; i < 2; ++i) {
      int c = wid * 2 + i;
      const short* ga = A + (size_t)(brow + c * 16 + crow) * K + kk + ccol;
      const short* gb = Bt + (size_t)(bcol + c * 16 + crow) * K + kk + ccol;
      gload_lds16(ga, &As[c * 512]);
      gload_lds16(gb, &Bs[c * 512]);
    }
    __syncthreads();
    bf16x8 af[4], bf[4];
#pragma unroll
    for (int m = 0; m < 4; ++m)
      af[m] = *(const bf16x8*)&As[(wr * 64 + m * 16 + r) * 32 + g * 8];
#pragma unroll
    for (int n = 0; n < 4; ++n)
      bf[n] = *(const bf16x8*)&Bs[(wc * 64 + n * 16 + r) * 32 + g * 8];
#pragma unroll
    for (int m = 0; m < 4; ++m)
#pragma unroll
      for (int n = 0; n < 4; ++n)
        acc[m][n] = __builtin_amdgcn_mfma_f32_16x16x32_bf16(af[m], bf[n], acc[m][n], 0, 0, 0);
  }

  if (MODE == 0) {
#pragma unroll
    for (int m = 0; m < 4; ++m)
#pragma unroll
      for (int n = 0; n < 4; ++n)
#pragma unroll
        for (int j = 0; j < 4; ++j) {
          int row = brow + wr * 64 + m * 16 + g * 4 + j;
          int col = bcol + wc * 64 + n * 16 + r;
          Cf[(size_t)row * N + col] = acc[m][n][j];
        }
  } else if (bcol < 4096) {
    // Q: row-major [h][s][128]
    unsigned short* dst = (unsigned short*)qb_ + (size_t)(bcol >> 7) * S_LEN * HD;
#pragma unroll
    for (int m = 0; m < 4; ++m)
#pragma unroll
      for (int n = 0; n < 4; ++n)
#pragma unroll
        for (int j = 0; j < 4; ++j) {
          int row = brow + wr * 64 + m * 16 + g * 4 + j;
          int d = wc * 64 + n * 16 + r;
          dst[(size_t)row * HD + d] = f2bf(acc[m][n][j]);
        }
  } else if (bcol < 5120) {
    // K: swizzled tiled
    char* base = (char*)kb_ + ((size_t)((bcol - 4096) >> 7) << 19);
#pragma unroll
    for (int m = 0; m < 4; ++m)
#pragma unroll
      for (int n = 0; n < 4; ++n)
#pragma unroll
        for (int j = 0; j < 4; ++j) {
          int row = brow + wr * 64 + m * 16 + g * 4 + j;
          int d = wc * 64 + n * 16 + r;
          int krow = row & 63;
          size_t off = ((size_t)(row >> 6) << 14) +
                       ((((krow << 8) + ((d >> 3) << 4)) ^ ((krow & 7) << 4)) + ((d & 7) << 1));
          *(unsigned short*)(base + off) = f2bf(acc[m][n][j]);
        }
  } else {
    // V: swizzled tiled (transposed: rows = d)
    char* base = (char*)vb_ + ((size_t)((bcol - 5120) >> 7) << 19);
#pragma unroll
    for (int m = 0; m < 4; ++m)
#pragma unroll
      for (int n = 0; n < 4; ++n)
#pragma unroll
        for (int j = 0; j < 4; ++j) {
          int row = brow + wr * 64 + m * 16 + g * 4 + j;  // s
          int d = wc * 64 + n * 16 + r;                   // head dim = vrow
          int sl = row & 63;
          size_t off = ((size_t)(row >> 6) << 14) +
                       ((((d << 7) + ((sl >> 3) << 4)) ^ ((d & 7) << 4)) + ((sl & 7) << 1));
          *(unsigned short*)(base + off) = f2bf(acc[m][n][j]);
        }
  }
}

// ---------------- kernel: RoPE in place; Q row-major, K swizzled-tiled -------
__global__ void rope_kernel(short* __restrict__ qbuf, short* __restrict__ kbuf,
                            const float* __restrict__ cosT, const float* __restrict__ sinT) {
  int idx = blockIdx.x * 256 + threadIdx.x;
  const int total = (NH + NKV) * S_LEN * 64;
  if (idx >= total) return;
  int d = idx & 63;
  int rowi = idx >> 6;
  int s;
  unsigned short *p1, *p2;
  if (rowi < NH * S_LEN) {
    unsigned short* base = (unsigned short*)qbuf + (size_t)rowi * HD;
    s = rowi & (S_LEN - 1);
    p1 = base + d; p2 = base + d + 64;
  } else {
    int kr = rowi - NH * S_LEN;          // kvh*2048 + s
    int kvh = kr >> 11; s = kr & (S_LEN - 1);
    char* base = (char*)kbuf + ((size_t)kvh << 19) + ((size_t)(s >> 6) << 14);
    int krow = s & 63, swz = (krow & 7) << 4;
    int dd = d + 64;
    p1 = (unsigned short*)(base + ((((krow << 8) + ((d >> 3) << 4)) ^ swz) + ((d & 7) << 1)));
    p2 = (unsigned short*)(base + ((((krow << 8) + ((dd >> 3) << 4)) ^ swz) + ((dd & 7) << 1)));
  }
  float x1 = bf2f(*p1);
  float x2 = bf2f(*p2);
  float c1 = cosT[s * HD + d], s1 = sinT[s * HD + d];
  *p1 = f2bf(x1 * c1 - x2 * s1);
  *p2 = f2bf(x2 * c1 + x1 * s1);   // cos/sin tables repeat at d+64
}

// ---------------- kernel: flash attention (causal, GQA 4:1) ----------------
// grid: (32 h, 32 qb-slots), block 256 = 4 waves; wave owns 16 q-rows.
// qb = perm[blockIdx.y] so any co-residency pattern balances per-CU work.
// All 1024 blocks resident at 4/CU (LDS 40KB, VGPR forced <=128).
// K/V staged via global_load_lds from pre-swizzled global tiles.
__global__ __launch_bounds__(256, 4) void attn_kernel(const short* __restrict__ qb_,
                                                      const short* __restrict__ kb_,
                                                      const short* __restrict__ vb_,
                                                      short* __restrict__ ctx) {
  const int h = blockIdx.x;
  const int byv = blockIdx.y;
  const int qb = (byv < 16) ? (byv * 2) : (63 - byv * 2);  // balanced perm
  const int kvh = h >> 2;
  const int tid = threadIdx.x, wid = tid >> 6, lane = tid & 63;
  const int r = lane & 15, g = lane >> 4;

  __shared__ short Ks[64 * 128];
  __shared__ short Vts[128 * 64];
  __shared__ short Ps[4][16 * 64];

  // Q fragments (row = r, k-slice per s4), kept in registers
  const unsigned short* qptr =
      (const unsigned short*)qb_ + ((size_t)h * S_LEN + qb * 64 + wid * 16) * HD;
  bf16x8 qf[4];
#pragma unroll
  for (int s4 = 0; s4 < 4; ++s4)
    qf[s4] = *(const bf16x8*)(qptr + (size_t)r * HD + s4 * 32 + g * 8);

  f32x4 oacc[8] = {};
  float m_run[4], l_run[4];
#pragma unroll
  for (int j = 0; j < 4; ++j) { m_run[j] = -1e30f; l_run[j] = 0.f; }

  const int nt = qb + 1;
  for (int kvt = 0; kvt < nt; ++kvt) {
    const char* ktile = (const char*)kb_ + (((size_t)kvh * 32 + kvt) << 14);
    const char* vtile = (const char*)vb_ + (((size_t)kvh * 32 + kvt) << 14);
    __syncthreads();  // previous tile's compute done with LDS
    // ---- stage K,V tiles: linear DMA, global already swizzled ----
#pragma unroll
    for (int i = 0; i < 4; ++i) {
      int chunk = i * 4 + wid;  // wave-uniform
      gload_lds16(ktile + chunk * 1024 + lane * 16, (char*)Ks + chunk * 1024);
      gload_lds16(vtile + chunk * 1024 + lane * 16, (char*)Vts + chunk * 1024);
    }
    __syncthreads();  // compiler drains vmcnt before barrier

    // ---- S = Q K^T (16 MFMA) ----
    f32x4 sv[4] = {};
    __builtin_amdgcn_s_setprio(1);
#pragma unroll
    for (int n = 0; n < 4; ++n) {
      int krow = n * 16 + r;
      int swz = (krow & 7) << 4;
#pragma unroll
      for (int s4 = 0; s4 < 4; ++s4) {
        bf16x8 kf = *(const bf16x8*)((const char*)Ks + ((krow * 256 + s4 * 64 + g * 16) ^ swz));
        sv[n] = __builtin_amdgcn_mfma_f32_16x16x32_bf16(qf[s4], kf, sv[n], 0, 0, 0);
      }
    }
    __builtin_amdgcn_s_setprio(0);

    // ---- scale + causal mask ----
    if (kvt == qb) {
#pragma unroll
      for (int n = 0; n < 4; ++n)
#pragma unroll
        for (int j = 0; j < 4; ++j) {
          int colg = kvt * 64 + n * 16 + r;
          int rowg = qb * 64 + wid * 16 + g * 4 + j;
          sv[n][j] = (colg <= rowg) ? sv[n][j] * ATT_SCALE : -1e30f;
        }
    } else {
#pragma unroll
      for (int n = 0; n < 4; ++n)
#pragma unroll
        for (int j = 0; j < 4; ++j) sv[n][j] *= ATT_SCALE;
    }

    // ---- online softmax (row = 16-lane group) ----
    float pmax[4];
#pragma unroll
    for (int j = 0; j < 4; ++j)
      pmax[j] = fmaxf(fmaxf(sv[0][j], sv[1][j]), fmaxf(sv[2][j], sv[3][j]));
#pragma unroll
    for (int msk = 1; msk <= 8; msk <<= 1)
#pragma unroll
      for (int j = 0; j < 4; ++j) pmax[j] = fmaxf(pmax[j], __shfl_xor(pmax[j], msk));

    float sf[4], rsum[4];
#pragma unroll
    for (int j = 0; j < 4; ++j) {
      float mn = fmaxf(m_run[j], pmax[j]);
      sf[j] = __expf(m_run[j] - mn);
      m_run[j] = mn;
      rsum[j] = 0.f;
    }
#pragma unroll
    for (int n = 0; n < 4; ++n)
#pragma unroll
      for (int j = 0; j < 4; ++j) {
        float p = __expf(sv[n][j] - m_run[j]);
        sv[n][j] = p;
        rsum[j] += p;
      }
#pragma unroll
    for (int msk = 1; msk <= 8; msk <<= 1)
#pragma unroll
      for (int j = 0; j < 4; ++j) rsum[j] += __shfl_xor(rsum[j], msk);
#pragma unroll
    for (int j = 0; j < 4; ++j) l_run[j] = l_run[j] * sf[j] + rsum[j];
#pragma unroll
    for (int t = 0; t < 8; ++t)
#pragma unroll
      for (int j = 0; j < 4; ++j) oacc[t][j] *= sf[j];

    // ---- P -> LDS (bf16, swizzled), per-wave private region ----
#pragma unroll
    for (int n = 0; n < 4; ++n)
#pragma unroll
      for (int j = 0; j < 4; ++j) {
        int prow = g * 4 + j, pcol = n * 16 + r;
        int poff = (prow * 128 + pcol * 2) ^ ((prow & 7) << 4);
        *(unsigned short*)((char*)&Ps[wid][0] + poff) = f2bf(sv[n][j]);
      }

    // ---- O += P V (16 MFMA) ----
    __builtin_amdgcn_s_setprio(1);
#pragma unroll
    for (int s4 = 0; s4 < 2; ++s4) {
      bf16x8 pf = *(const bf16x8*)((const char*)&Ps[wid][0] +
                                   ((r * 128 + s4 * 64 + g * 16) ^ ((r & 7) << 4)));
#pragma unroll
      for (int t = 0; t < 8; ++t) {
        int vrow = t * 16 + r;
        bf16x8 vf = *(const bf16x8*)((const char*)Vts +
                                     ((vrow * 128 + s4 * 64 + g * 16) ^ ((vrow & 7) << 4)));
        oacc[t] = __builtin_amdgcn_mfma_f32_16x16x32_bf16(pf, vf, oacc[t], 0, 0, 0);
      }
    }
    __builtin_amdgcn_s_setprio(0);
  }

  // ---- epilogue: ctx[s][h*128+d] bf16 ----
  float inv[4];
#pragma unroll
  for (int j = 0; j < 4; ++j) inv[j] = 1.0f / l_run[j];
#pragma unroll
  for (int t = 0; t < 8; ++t)
#pragma unroll
    for (int j = 0; j < 4; ++j) {
      int rowg = qb * 64 + wid * 16 + g * 4 + j;
      int colg = h * HD + t * 16 + r;
      ((unsigned short*)ctx)[(size_t)rowg * HID + colg] = f2bf(oacc[t][j] * inv[j]);
    }
}

// ---------------- launcher ----------------
extern "C" void kernel_launch(void* const* d_in, const int* in_sizes, int n_in,
                              void* d_out, int out_size, void* d_ws, size_t ws_size,
                              hipStream_t stream) {
  const float* hidden = (const float*)d_in[0];
  const float* cosT   = (const float*)d_in[1];
  const float* sinT   = (const float*)d_in[2];
  // d_in[3] = causal mask (implemented analytically)
  const float* Wq = (const float*)d_in[4];
  const float* Wk = (const float*)d_in[5];
  const float* Wv = (const float*)d_in[6];
  const float* Wo = (const float*)d_in[7];
  float* out = (float*)d_out;

  char* ws = (char*)d_ws;
  short* hid_bf = (short*)(ws);                        // 16 MB
  short* Wcat   = (short*)(ws + 16777216);             // 48 MB  [6144][4096] bf16 (B^T)
  short* WoT    = (short*)(ws + 67108864);             // 32 MB  [4096][4096] bf16 (B^T)
  short* qbuf   = (short*)(ws + 100663296);            // 16 MB  [32][2048][128]
  short* kbuf   = (short*)(ws + 117440512);            // 4 MB   swizzled tiles
  short* vbuf   = (short*)(ws + 121634816);            // 4 MB   swizzled tiles
  short* ctx    = (short*)(ws + 125829120);            // 16 MB  [2048][4096]

  // 1) convert hidden fp32 -> bf16
  cvt_f32_bf16_kernel<<<4096, 256, 0, stream>>>(hidden, hid_bf, S_LEN * HID);

  // 2) transpose-convert weights into B^T bf16 layout
  transpose_cvt_kernel<<<dim3(128, 128), 256, 0, stream>>>(Wq, Wcat, HID, 4096);
  transpose_cvt_kernel<<<dim3(32, 128), 256, 0, stream>>>(Wk, Wcat + (size_t)4096 * HID, HID, 1024);
  transpose_cvt_kernel<<<dim3(32, 128), 256, 0, stream>>>(Wv, Wcat + (size_t)5120 * HID, HID, 1024);
  transpose_cvt_kernel<<<dim3(128, 128), 256, 0, stream>>>(Wo, WoT, HID, 4096);

  // 3) QKV projection GEMM (M=2048, N=6144, K=4096), scatter epilogue
  gemm_bt_kernel<1><<<dim3(48, 16), 256, 0, stream>>>(hid_bf, Wcat, S_LEN, NQKV, HID,
                                                      nullptr, qbuf, kbuf, vbuf);

  // 4) RoPE on Q and K (K in swizzled layout)
  rope_kernel<<<20480, 256, 0, stream>>>(qbuf, kbuf, cosT, sinT);

  // 5) causal GQA flash attention -> ctx bf16 [2048][4096]
  attn_kernel<<<dim3(32, 32), 256, 0, stream>>>(qbuf, kbuf, vbuf, ctx);

  // 6) output projection GEMM -> fp32 out
  gemm_bt_kernel<0><<<dim3(32, 16), 256, 0, stream>>>(ctx, WoT, S_LEN, HID, HID,
                                                      out, nullptr, nullptr, nullptr);
}

// Round 4
// 365.241 us; speedup vs baseline: 1.4952x; 1.1322x over previous
//
#include <hip/hip_runtime.h>
#include <hip/hip_bf16.h>
#include <cstdint>
#include <cstddef>

// ---------------- common types/helpers ----------------
typedef __attribute__((ext_vector_type(8))) short bf16x8;
typedef __attribute__((ext_vector_type(4))) float f32x4;
typedef __attribute__((ext_vector_type(4))) unsigned int u32x4;

__device__ __forceinline__ unsigned short f2bf(float f) {
  __hip_bfloat16 h = __float2bfloat16(f);
  return *reinterpret_cast<unsigned short*>(&h);
}
__device__ __forceinline__ float bf2f(unsigned short u) {
  __hip_bfloat16 h = *reinterpret_cast<__hip_bfloat16*>(&u);
  return __bfloat162float(h);
}

typedef const __attribute__((address_space(1))) void gas_void;
typedef __attribute__((address_space(3))) void las_void;
__device__ __forceinline__ void gload_lds16(const void* g, void* l) {
  __builtin_amdgcn_global_load_lds((gas_void*)g, (las_void*)l, 16, 0, 0);
}

// ---------------- problem constants ----------------
#define S_LEN 2048
#define HID 4096
#define NH 32
#define NKV 8
#define HD 128
#define NQKV 6144           // 4096 + 1024 + 1024
static const float ATT_SCALE = 0.08838834764831845f; // 128^-0.5

// K global layout: [kvh][kvt(32)][16KB tile], element (krow=s&63, d) at byte
//   (((krow<<8) + ((d>>3)<<4)) ^ ((krow&7)<<4)) + ((d&7)<<1)
// V global layout: [kvh][kvt(32)][16KB tile], element (vrow=d, sl=s&63) at byte
//   (((vrow<<7) + ((sl>>3)<<4)) ^ ((vrow&7)<<4)) + ((sl&7)<<1)
// These equal the swizzled LDS image, so global_load_lds (linear dest) +
// swizzled ds_read in attn is correct (both-sides swizzle, rule 21).

// ---------------- kernel: fp32 -> bf16 convert (hidden) ----------------
__global__ void cvt_f32_bf16_kernel(const float* __restrict__ src,
                                    short* __restrict__ dst, int n) {
  int i = (blockIdx.x * 256 + threadIdx.x) * 8;
  if (i >= n) return;
  f32x4 a = *(const f32x4*)(src + i);
  f32x4 b = *(const f32x4*)(src + i + 4);
  unsigned short t[8];
#pragma unroll
  for (int k = 0; k < 4; ++k) { t[k] = f2bf(a[k]); t[4 + k] = f2bf(b[k]); }
  *(u32x4*)(dst + i) = *(const u32x4*)t;
}

// ---------------- kernel: fp32 [K][N] -> bf16 [N][K] transpose-convert --------
// grid: (N/32, K/32), block 256 (32x8)
__global__ void transpose_cvt_kernel(const float* __restrict__ src,
                                     short* __restrict__ dst, int K, int N) {
  __shared__ float tile[32][33];
  int tx = threadIdx.x & 31, ty = threadIdx.x >> 5;
  int bx = blockIdx.x, by = blockIdx.y;
#pragma unroll
  for (int i = 0; i < 4; ++i) {
    int kr = ty + i * 8;
    tile[kr][tx] = src[(size_t)(by * 32 + kr) * N + bx * 32 + tx];
  }
  __syncthreads();
#pragma unroll
  for (int i = 0; i < 4; ++i) {
    int nc = ty + i * 8;
    dst[(size_t)(bx * 32 + nc) * K + by * 32 + tx] = (short)f2bf(tile[tx][nc]);
  }
}

// ---------------- kernel: bf16 GEMM  C[M,N] = A[M,K] * Bt[N,K]^T -------------
// m97 structure: 128x128 tile, BK=32, 4 waves, global_load_lds width 16.
// MODE 0: write fp32 C.   MODE 1: scatter QKV (bf16): Q row-major,
//                                 K/V in pre-swizzled tiled layout (see top).
template <int MODE>
__global__ void gemm_bt_kernel(const short* __restrict__ A, const short* __restrict__ Bt,
                               int M, int N, int K,
                               float* __restrict__ Cf,
                               short* __restrict__ qb_, short* __restrict__ kb_,
                               short* __restrict__ vb_) {
  __shared__ short As[128 * 32];
  __shared__ short Bs[128 * 32];
  const int tid = threadIdx.x;
  const int wid = tid >> 6, lane = tid & 63;
  const int brow = blockIdx.y * 128, bcol = blockIdx.x * 128;
  const int wr = wid >> 1, wc = wid & 1;
  const int r = lane & 15, g = lane >> 4;
  const int crow = lane >> 2;        // row within 16-row chunk
  const int ccol = (lane & 3) * 8;   // element col within 32

  f32x4 acc[4][4] = {};

  for (int kk = 0; kk < K; kk += 32) {
    __syncthreads();
#pragma unroll
    for (int i = 0; i < 2; ++i) {
      int c = wid * 2 + i;
      const short* ga = A + (size_t)(brow + c * 16 + crow) * K + kk + ccol;
      const short* gb = Bt + (size_t)(bcol + c * 16 + crow) * K + kk + ccol;
      gload_lds16(ga, &As[c * 512]);
      gload_lds16(gb, &Bs[c * 512]);
    }
    __syncthreads();
    bf16x8 af[4], bf[4];
#pragma unroll
    for (int m = 0; m < 4; ++m)
      af[m] = *(const bf16x8*)&As[(wr * 64 + m * 16 + r) * 32 + g * 8];
#pragma unroll
    for (int n = 0; n < 4; ++n)
      bf[n] = *(const bf16x8*)&Bs[(wc * 64 + n * 16 + r) * 32 + g * 8];
#pragma unroll
    for (int m = 0; m < 4; ++m)
#pragma unroll
      for (int n = 0; n < 4; ++n)
        acc[m][n] = __builtin_amdgcn_mfma_f32_16x16x32_bf16(af[m], bf[n], acc[m][n], 0, 0, 0);
  }

  if (MODE == 0) {
#pragma unroll
    for (int m = 0; m < 4; ++m)
#pragma unroll
      for (int n = 0; n < 4; ++n)
#pragma unroll
        for (int j = 0; j < 4; ++j) {
          int row = brow + wr * 64 + m * 16 + g * 4 + j;
          int col = bcol + wc * 64 + n * 16 + r;
          Cf[(size_t)row * N + col] = acc[m][n][j];
        }
  } else if (bcol < 4096) {
    // Q: row-major [h][s][128]
    unsigned short* dst = (unsigned short*)qb_ + (size_t)(bcol >> 7) * S_LEN * HD;
#pragma unroll
    for (int m = 0; m < 4; ++m)
#pragma unroll
      for (int n = 0; n < 4; ++n)
#pragma unroll
        for (int j = 0; j < 4; ++j) {
          int row = brow + wr * 64 + m * 16 + g * 4 + j;
          int d = wc * 64 + n * 16 + r;
          dst[(size_t)row * HD + d] = f2bf(acc[m][n][j]);
        }
  } else if (bcol < 5120) {
    // K: swizzled tiled
    char* base = (char*)kb_ + ((size_t)((bcol - 4096) >> 7) << 19);
#pragma unroll
    for (int m = 0; m < 4; ++m)
#pragma unroll
      for (int n = 0; n < 4; ++n)
#pragma unroll
        for (int j = 0; j < 4; ++j) {
          int row = brow + wr * 64 + m * 16 + g * 4 + j;
          int d = wc * 64 + n * 16 + r;
          int krow = row & 63;
          size_t off = ((size_t)(row >> 6) << 14) +
                       ((((krow << 8) + ((d >> 3) << 4)) ^ ((krow & 7) << 4)) + ((d & 7) << 1));
          *(unsigned short*)(base + off) = f2bf(acc[m][n][j]);
        }
  } else {
    // V: swizzled tiled (transposed: rows = d)
    char* base = (char*)vb_ + ((size_t)((bcol - 5120) >> 7) << 19);
#pragma unroll
    for (int m = 0; m < 4; ++m)
#pragma unroll
      for (int n = 0; n < 4; ++n)
#pragma unroll
        for (int j = 0; j < 4; ++j) {
          int row = brow + wr * 64 + m * 16 + g * 4 + j;  // s
          int d = wc * 64 + n * 16 + r;                   // head dim = vrow
          int sl = row & 63;
          size_t off = ((size_t)(row >> 6) << 14) +
                       ((((d << 7) + ((sl >> 3) << 4)) ^ ((d & 7) << 4)) + ((sl & 7) << 1));
          *(unsigned short*)(base + off) = f2bf(acc[m][n][j]);
        }
  }
}

// ---------------- kernel: RoPE in place; Q row-major, K swizzled-tiled -------
__global__ void rope_kernel(short* __restrict__ qbuf, short* __restrict__ kbuf,
                            const float* __restrict__ cosT, const float* __restrict__ sinT) {
  int idx = blockIdx.x * 256 + threadIdx.x;
  const int total = (NH + NKV) * S_LEN * 64;
  if (idx >= total) return;
  int d = idx & 63;
  int rowi = idx >> 6;
  int s;
  unsigned short *p1, *p2;
  if (rowi < NH * S_LEN) {
    unsigned short* base = (unsigned short*)qbuf + (size_t)rowi * HD;
    s = rowi & (S_LEN - 1);
    p1 = base + d; p2 = base + d + 64;
  } else {
    int kr = rowi - NH * S_LEN;          // kvh*2048 + s
    int kvh = kr >> 11; s = kr & (S_LEN - 1);
    char* base = (char*)kbuf + ((size_t)kvh << 19) + ((size_t)(s >> 6) << 14);
    int krow = s & 63, swz = (krow & 7) << 4;
    int dd = d + 64;
    p1 = (unsigned short*)(base + ((((krow << 8) + ((d >> 3) << 4)) ^ swz) + ((d & 7) << 1)));
    p2 = (unsigned short*)(base + ((((krow << 8) + ((dd >> 3) << 4)) ^ swz) + ((dd & 7) << 1)));
  }
  float x1 = bf2f(*p1);
  float x2 = bf2f(*p2);
  float c1 = cosT[s * HD + d], s1 = sinT[s * HD + d];
  *p1 = f2bf(x1 * c1 - x2 * s1);
  *p2 = f2bf(x2 * c1 + x1 * s1);   // cos/sin tables repeat at d+64
}

// ---------------- kernel: flash attention (causal, GQA 4:1) ----------------
// 256 blocks x 512 threads (8 waves). kvh = bid&7 (XCD affinity: round-robin
// dispatch puts all blocks of one kvh on one XCD -> K/V (1MB) L2-resident).
// Block = head h, two q-sections qb2 in {slot, 15-slot} of 128 rows each ->
// exactly 34 KV-tiles per block (uniform). Wave owns 16 q-rows.
// Double-buffered K/V staging via global_load_lds (2-phase pipeline: prefetch
// tile t+1 issued before computing tile t; barrier at loop top is the drain).
__global__ __launch_bounds__(512, 2) void attn_kernel(const short* __restrict__ qb_,
                                                      const short* __restrict__ kb_,
                                                      const short* __restrict__ vb_,
                                                      short* __restrict__ ctx) {
  const int bid = blockIdx.x;
  const int kvh = bid & 7;
  const int idx = bid >> 3;
  const int h = kvh * 4 + (idx & 3);
  const int slot = idx >> 2;            // 0..7
  const int tid = threadIdx.x, wid = tid >> 6, lane = tid & 63;
  const int r = lane & 15, g = lane >> 4;

  __shared__ short Ks[2][64 * 128];
  __shared__ short Vts[2][128 * 64];
  __shared__ short Ps[8][16 * 64];

  const int qb2s[2] = { slot, 15 - slot };
  const int nt0 = 2 * qb2s[0] + 2;
  const int T = 34;

  const char* kvbase_k = (const char*)kb_ + ((size_t)kvh << 19);
  const char* kvbase_v = (const char*)vb_ + ((size_t)kvh << 19);

  auto stage = [&](int tg, int b) {
    int kvt = (tg < nt0) ? tg : (tg - nt0);
    const char* kt = kvbase_k + ((size_t)kvt << 14);
    const char* vt = kvbase_v + ((size_t)kvt << 14);
#pragma unroll
    for (int i = 0; i < 2; ++i) {
      int ch = i * 8 + wid;   // wave-uniform chunk 0..15
      gload_lds16(kt + ch * 1024 + lane * 16, (char*)&Ks[b][0] + ch * 1024);
      gload_lds16(vt + ch * 1024 + lane * 16, (char*)&Vts[b][0] + ch * 1024);
    }
  };

  stage(0, 0);
  int cur = 0, tglob = 0;

  for (int sec = 0; sec < 2; ++sec) {
    const int qb2 = qb2s[sec];
    const int nt = 2 * qb2 + 2;
    const int rowbase = qb2 * 128 + wid * 16;

    // Q fragments for this section (row = r within wave's 16 rows)
    const unsigned short* qptr =
        (const unsigned short*)qb_ + ((size_t)h * S_LEN + rowbase) * HD;
    bf16x8 qf[4];
#pragma unroll
    for (int s4 = 0; s4 < 4; ++s4)
      qf[s4] = *(const bf16x8*)(qptr + (size_t)r * HD + s4 * 32 + g * 8);

    f32x4 oacc[8] = {};
    float m_run[4], l_run[4];
#pragma unroll
    for (int j = 0; j < 4; ++j) { m_run[j] = -1e30f; l_run[j] = 0.f; }

    for (int kvt = 0; kvt < nt; ++kvt, ++tglob) {
      __syncthreads();  // drains prev stage (vmcnt) + all waves done with buf[cur^1]
      if (tglob + 1 < T) stage(tglob + 1, cur ^ 1);

      const char* Kc = (const char*)&Ks[cur][0];
      const char* Vc = (const char*)&Vts[cur][0];

      // ---- S = Q K^T (16 MFMA) ----
      f32x4 sv[4] = {};
      __builtin_amdgcn_s_setprio(1);
#pragma unroll
      for (int n = 0; n < 4; ++n) {
        int krow = n * 16 + r;
        int swz = (krow & 7) << 4;
#pragma unroll
        for (int s4 = 0; s4 < 4; ++s4) {
          bf16x8 kf = *(const bf16x8*)(Kc + ((krow * 256 + s4 * 64 + g * 16) ^ swz));
          sv[n] = __builtin_amdgcn_mfma_f32_16x16x32_bf16(qf[s4], kf, sv[n], 0, 0, 0);
        }
      }
      __builtin_amdgcn_s_setprio(0);

      // ---- scale + causal mask (wave-uniform branch) ----
      if (kvt * 64 + 63 > rowbase) {
#pragma unroll
        for (int n = 0; n < 4; ++n)
#pragma unroll
          for (int j = 0; j < 4; ++j) {
            int colg = kvt * 64 + n * 16 + r;
            int rowg = rowbase + g * 4 + j;
            sv[n][j] = (colg <= rowg) ? sv[n][j] * ATT_SCALE : -1e30f;
          }
      } else {
#pragma unroll
        for (int n = 0; n < 4; ++n)
#pragma unroll
          for (int j = 0; j < 4; ++j) sv[n][j] *= ATT_SCALE;
      }

      // ---- online softmax (row = 16-lane group) ----
      float pmax[4];
#pragma unroll
      for (int j = 0; j < 4; ++j)
        pmax[j] = fmaxf(fmaxf(sv[0][j], sv[1][j]), fmaxf(sv[2][j], sv[3][j]));
#pragma unroll
      for (int msk = 1; msk <= 8; msk <<= 1)
#pragma unroll
        for (int j = 0; j < 4; ++j) pmax[j] = fmaxf(pmax[j], __shfl_xor(pmax[j], msk));

      float sf[4], rsum[4];
#pragma unroll
      for (int j = 0; j < 4; ++j) {
        float mn = fmaxf(m_run[j], pmax[j]);
        sf[j] = __expf(m_run[j] - mn);
        m_run[j] = mn;
        rsum[j] = 0.f;
      }
#pragma unroll
      for (int n = 0; n < 4; ++n)
#pragma unroll
        for (int j = 0; j < 4; ++j) {
          float p = __expf(sv[n][j] - m_run[j]);
          sv[n][j] = p;
          rsum[j] += p;
        }
#pragma unroll
      for (int msk = 1; msk <= 8; msk <<= 1)
#pragma unroll
        for (int j = 0; j < 4; ++j) rsum[j] += __shfl_xor(rsum[j], msk);
#pragma unroll
      for (int j = 0; j < 4; ++j) l_run[j] = l_run[j] * sf[j] + rsum[j];
#pragma unroll
      for (int t = 0; t < 8; ++t)
#pragma unroll
        for (int j = 0; j < 4; ++j) oacc[t][j] *= sf[j];

      // ---- P -> LDS (bf16, swizzled), per-wave private region ----
#pragma unroll
      for (int n = 0; n < 4; ++n)
#pragma unroll
        for (int j = 0; j < 4; ++j) {
          int prow = g * 4 + j, pcol = n * 16 + r;
          int poff = (prow * 128 + pcol * 2) ^ ((prow & 7) << 4);
          *(unsigned short*)((char*)&Ps[wid][0] + poff) = f2bf(sv[n][j]);
        }

      // ---- O += P V (16 MFMA) ----
      __builtin_amdgcn_s_setprio(1);
#pragma unroll
      for (int s4 = 0; s4 < 2; ++s4) {
        bf16x8 pf = *(const bf16x8*)((const char*)&Ps[wid][0] +
                                     ((r * 128 + s4 * 64 + g * 16) ^ ((r & 7) << 4)));
#pragma unroll
        for (int t = 0; t < 8; ++t) {
          int vrow = t * 16 + r;
          bf16x8 vf = *(const bf16x8*)(Vc + ((vrow * 128 + s4 * 64 + g * 16) ^ ((vrow & 7) << 4)));
          oacc[t] = __builtin_amdgcn_mfma_f32_16x16x32_bf16(pf, vf, oacc[t], 0, 0, 0);
        }
      }
      __builtin_amdgcn_s_setprio(0);
      cur ^= 1;
    }

    // ---- epilogue for this section: ctx[s][h*128+d] bf16 ----
    float inv[4];
#pragma unroll
    for (int j = 0; j < 4; ++j) inv[j] = 1.0f / l_run[j];
#pragma unroll
    for (int t = 0; t < 8; ++t)
#pragma unroll
      for (int j = 0; j < 4; ++j) {
        int rowg = rowbase + g * 4 + j;
        int colg = h * HD + t * 16 + r;
        ((unsigned short*)ctx)[(size_t)rowg * HID + colg] = f2bf(oacc[t][j] * inv[j]);
      }
  }
}

// ---------------- launcher ----------------
extern "C" void kernel_launch(void* const* d_in, const int* in_sizes, int n_in,
                              void* d_out, int out_size, void* d_ws, size_t ws_size,
                              hipStream_t stream) {
  const float* hidden = (const float*)d_in[0];
  const float* cosT   = (const float*)d_in[1];
  const float* sinT   = (const float*)d_in[2];
  // d_in[3] = causal mask (implemented analytically)
  const float* Wq = (const float*)d_in[4];
  const float* Wk = (const float*)d_in[5];
  const float* Wv = (const float*)d_in[6];
  const float* Wo = (const float*)d_in[7];
  float* out = (float*)d_out;

  char* ws = (char*)d_ws;
  short* hid_bf = (short*)(ws);                        // 16 MB
  short* Wcat   = (short*)(ws + 16777216);             // 48 MB  [6144][4096] bf16 (B^T)
  short* WoT    = (short*)(ws + 67108864);             // 32 MB  [4096][4096] bf16 (B^T)
  short* qbuf   = (short*)(ws + 100663296);            // 16 MB  [32][2048][128]
  short* kbuf   = (short*)(ws + 117440512);            // 4 MB   swizzled tiles
  short* vbuf   = (short*)(ws + 121634816);            // 4 MB   swizzled tiles
  short* ctx    = (short*)(ws + 125829120);            // 16 MB  [2048][4096]

  // 1) convert hidden fp32 -> bf16
  cvt_f32_bf16_kernel<<<4096, 256, 0, stream>>>(hidden, hid_bf, S_LEN * HID);

  // 2) transpose-convert weights into B^T bf16 layout
  transpose_cvt_kernel<<<dim3(128, 128), 256, 0, stream>>>(Wq, Wcat, HID, 4096);
  transpose_cvt_kernel<<<dim3(32, 128), 256, 0, stream>>>(Wk, Wcat + (size_t)4096 * HID, HID, 1024);
  transpose_cvt_kernel<<<dim3(32, 128), 256, 0, stream>>>(Wv, Wcat + (size_t)5120 * HID, HID, 1024);
  transpose_cvt_kernel<<<dim3(128, 128), 256, 0, stream>>>(Wo, WoT, HID, 4096);

  // 3) QKV projection GEMM (M=2048, N=6144, K=4096), scatter epilogue
  gemm_bt_kernel<1><<<dim3(48, 16), 256, 0, stream>>>(hid_bf, Wcat, S_LEN, NQKV, HID,
                                                      nullptr, qbuf, kbuf, vbuf);

  // 4) RoPE on Q and K (K in swizzled layout)
  rope_kernel<<<20480, 256, 0, stream>>>(qbuf, kbuf, cosT, sinT);

  // 5) causal GQA flash attention -> ctx bf16 [2048][4096]
  attn_kernel<<<256, 512, 0, stream>>>(qbuf, kbuf, vbuf, ctx);

  // 6) output projection GEMM -> fp32 out
  gemm_bt_kernel<0><<<dim3(32, 16), 256, 0, stream>>>(ctx, WoT, S_LEN, HID, HID,
                                                      out, nullptr, nullptr, nullptr);
}